// Round 1
// baseline (311.639 us; speedup 1.0000x reference)
//
#include <hip/hip_runtime.h>

// DLRM InteractionArch: B=16384, D=128, F=26, N=27
// out[b] = concat(dense[b] (128 fp32), triu(X X^T, k=1) (351 fp32))
// where X = concat(dense[b][None,:], sparse[b]) : 27 x 128.
//
// One wave per batch element. Stage tile to LDS as fp16, compute the full
// 32x32 Gram with 8x v_mfma_f32_32x32x16_f16 (same fragment as A and B),
// extract upper triangle via LDS scatter, coalesced dword stores.

#define FEAT 26
#define NROW 27
#define DDIM 128
#define NTRI 351            // 27*26/2
#define OUTW 479            // 128 + 351
#define LDST 136            // LDS row stride in fp16 (16B-aligned rows)

typedef _Float16 half2v __attribute__((ext_vector_type(2)));
typedef _Float16 half4v __attribute__((ext_vector_type(4)));
typedef _Float16 half8v __attribute__((ext_vector_type(8)));
typedef float    f32x16 __attribute__((ext_vector_type(16)));

__global__ __launch_bounds__(256) void interaction_kernel(
    const float* __restrict__ dense,
    const float* __restrict__ sparse,
    float* __restrict__ out)
{
    __shared__ _Float16 Xs[4][32][LDST];   // per-wave 27x128 tile (fp16), pad rows 27..31 unused
    __shared__ float    Tri[4][NTRI + 1];  // per-wave triangle staging

    const int lane = threadIdx.x & 63;
    const int w    = threadIdx.x >> 6;
    const long b   = (long)blockIdx.x * 4 + w;

    const float* dn   = dense  + b * DDIM;
    const float* sp   = sparse + b * (FEAT * DDIM);
    float*       orow = out    + b * OUTW;

    // ---- stage dense row: fp32 copy to out (dword stores; orow is only 4B aligned),
    //      fp16 copy to LDS row 0
    {
        float2 v = *(const float2*)(dn + lane * 2);
        orow[lane * 2 + 0] = v.x;
        orow[lane * 2 + 1] = v.y;
        half2v h;
        h.x = (_Float16)v.x; h.y = (_Float16)v.y;
        *(half2v*)(&Xs[w][0][lane * 2]) = h;
    }

    // ---- stage sparse rows 1..26: 26*128 = 3328 floats = 832 float4, 13 iters x 64 lanes
#pragma unroll
    for (int t = 0; t < 13; ++t) {
        int idx = t * 64 + lane;           // 0..831
        float4 v = *(const float4*)(sp + idx * 4);
        int row = 1 + (idx >> 5);          // 1..26
        int col = (idx & 31) * 4;          // 0..124
        half4v h;
        h.x = (_Float16)v.x; h.y = (_Float16)v.y;
        h.z = (_Float16)v.z; h.w = (_Float16)v.w;
        *(half4v*)(&Xs[w][row][col]) = h;
    }
    __syncthreads();

    // ---- Gram via MFMA: C = X X^T (32x32, rows/cols >= 27 are garbage, never read).
    // A-frag == B-frag: lane l holds X[l&31][s*16 + (l>>5)*8 + j], j=0..7.
    const int j0 = lane & 31;              // C/D column held by this lane
    const int q  = lane >> 5;
    const half8v* fp = (const half8v*)(&Xs[w][j0][q * 8]);

    f32x16 acc = {0,0,0,0,0,0,0,0,0,0,0,0,0,0,0,0};
#pragma unroll
    for (int s = 0; s < 8; ++s) {
        half8v f = fp[2 * s];              // advance 16 halfs (32B) per K-step
        acc = __builtin_amdgcn_mfma_f32_32x32x16_f16(f, f, acc, 0, 0, 0);
    }

    // ---- extract upper triangle (i<j<27) into Tri in triu_indices order.
    // C/D layout (HW-verified): col = lane&31, row = (reg&3) + 8*(reg>>2) + 4*(lane>>5)
#pragma unroll
    for (int reg = 0; reg < 16; ++reg) {
        int row = (reg & 3) + 8 * (reg >> 2) + 4 * q;
        if (row < j0 && j0 < NROW) {
            int t = row * (2 * NROW - row - 1) / 2 + (j0 - row - 1);
            Tri[w][t] = acc[reg];
        }
    }
    __syncthreads();

    // ---- coalesced store of the triangle
    for (int idx = lane; idx < NTRI; idx += 64)
        orow[DDIM + idx] = Tri[w][idx];
}

extern "C" void kernel_launch(void* const* d_in, const int* in_sizes, int n_in,
                              void* d_out, int out_size, void* d_ws, size_t ws_size,
                              hipStream_t stream) {
    const float* dense  = (const float*)d_in[0];
    const float* sparse = (const float*)d_in[1];
    float* out = (float*)d_out;
    // 16384 batches, 1 wave each, 4 waves per 256-thread block -> 4096 blocks
    interaction_kernel<<<4096, 256, 0, stream>>>(dense, sparse, out);
}